// Round 1
// baseline (544.613 us; speedup 1.0000x reference)
//
#include <hip/hip_runtime.h>

// spectralAgg: per-(batch,patch) channel-attention (DANet CAM) on 8x8 grid of
// 64x64 patches of a (8,64,512,512) fp32 tensor.
// energy = p p^T (64x64), attention = softmax(-energy) rowwise, out = (1+gamma)*A p.

#define NC   64         // channels
#define NW   512        // width
#define HWs  262144     // H*W
#define PS   64         // patch side
#define TI   128        // i-tile (2 patch rows x 64 cols)
#define SG   132        // stage LDS stride (floats), %4==0 for b128, swizzled
#define SE   68         // energy LDS stride
#define SA   68         // A^T LDS stride
#define NST  32         // 4096 / TI

__device__ __forceinline__ void load_stage(const float* __restrict__ xp,
                                           float* __restrict__ stage,
                                           int st, int t) {
  // tile: channels 0..63 x i=0..127 (rows st*2, st*2+1 of the patch)
  // thread loads 8 float4; per-wave: 2 channels x 2 rows x 16 quads (coalesced 256B runs)
#pragma unroll
  for (int k = 0; k < 8; ++k) {
    const int L   = t + k * 256;
    const int c   = L >> 5;
    const int rem = L & 31;
    const int rl  = rem >> 4;
    const int q   = rem & 15;
    const float4 v = *(const float4*)(xp + (size_t)c * HWs + (size_t)(st * 2 + rl) * NW + q * 4);
    const int i0 = rl * 64 + q * 4;
    const int is = i0 ^ ((c >> 3) << 2);     // XOR swizzle: conflict-free reads AND writes
    *(float4*)(&stage[c * SG + is]) = v;
  }
}

extern "C" __global__ __launch_bounds__(256, 2)
void spectralAgg_kernel(const float* __restrict__ x, const float* __restrict__ g,
                        float* __restrict__ out) {
  __shared__ float stage[NC * SG];   // 33792 B
  __shared__ float E[NC * SE];       // 17408 B  energy[c][d]
  __shared__ float AT[NC * SA];      // 17408 B  attention^T[d][c]

  const int wg = blockIdx.x;         // 512 = 8 batches * 64 patches
  const int b  = wg >> 6;
  const int pp = wg & 63;
  const int pr = pp >> 3, pc = pp & 7;
  const int t  = threadIdx.x;
  const int wv = t >> 6;
  const int ln = t & 63;
  const int cb = ln & 7;             // c-block (8 channels)
  const int db = ln >> 3;            // d-block (Gram) / i-block (PV)

  const size_t pbase = (size_t)b * NC * HWs + (size_t)(pr * PS) * NW + (size_t)(pc * PS);
  const float* xp = x + pbase;
  float* op = out + pbase;

  // ---------------- Phase 1: Gram (energy) ----------------
  float acc[8][8];
#pragma unroll
  for (int i = 0; i < 8; ++i)
#pragma unroll
    for (int j = 0; j < 8; ++j) acc[i][j] = 0.f;

  for (int st = 0; st < NST; ++st) {
    load_stage(xp, stage, st, t);
    __syncthreads();
    const int ibase = wv * 32;       // wave's i-subrange within the tile
#pragma unroll 1
    for (int ii = 0; ii < 32; ii += 4) {
      const int i0 = ibase + ii;
      float4 af[8], bf[8];
#pragma unroll
      for (int j = 0; j < 8; ++j) {
        const int ca = cb * 8 + j;   // ca>>3 == cb
        af[j] = *(const float4*)(&stage[ca * SG + (i0 ^ (cb << 2))]);
        const int cd = db * 8 + j;   // cd>>3 == db
        bf[j] = *(const float4*)(&stage[cd * SG + (i0 ^ (db << 2))]);
      }
#pragma unroll
      for (int j = 0; j < 8; ++j) {
        const float4 a4 = af[j];
#pragma unroll
        for (int jj = 0; jj < 8; ++jj) {
          const float4 b4 = bf[jj];
          float s = acc[j][jj];
          s = fmaf(a4.x, b4.x, s);
          s = fmaf(a4.y, b4.y, s);
          s = fmaf(a4.z, b4.z, s);
          s = fmaf(a4.w, b4.w, s);
          acc[j][jj] = s;
        }
      }
    }
    __syncthreads();
  }

  // reduce 4 per-wave partial Grams into E (serialized, float4 RMW)
  for (int w = 0; w < 4; ++w) {
    if (wv == w) {
#pragma unroll
      for (int j = 0; j < 8; ++j) {
        float4* e = (float4*)&E[(cb * 8 + j) * SE + db * 8];
        if (w == 0) {
          e[0] = make_float4(acc[j][0], acc[j][1], acc[j][2], acc[j][3]);
          e[1] = make_float4(acc[j][4], acc[j][5], acc[j][6], acc[j][7]);
        } else {
          float4 p0 = e[0], p1 = e[1];
          p0.x += acc[j][0]; p0.y += acc[j][1]; p0.z += acc[j][2]; p0.w += acc[j][3];
          p1.x += acc[j][4]; p1.y += acc[j][5]; p1.z += acc[j][6]; p1.w += acc[j][7];
          e[0] = p0; e[1] = p1;
        }
      }
    }
    __syncthreads();
  }

  // ---------------- Phase 2: softmax(-E) rowwise -> AT[d][c] ----------------
  // softmax(max-e) == softmax(-e); stabilize with row min: w = exp(min - e)
#pragma unroll 1
  for (int rr = 0; rr < 16; ++rr) {
    const int c = wv * 16 + rr;
    const float e = E[c * SE + ln];
    float m = e;
#pragma unroll
    for (int o = 32; o; o >>= 1) m = fminf(m, __shfl_xor(m, o));
    const float wt = expf(m - e);
    float s = wt;
#pragma unroll
    for (int o = 32; o; o >>= 1) s += __shfl_xor(s, o);
    AT[ln * SA + c] = wt / s;
  }
  __syncthreads();

  // ---------------- Phase 3: out = (1+gamma) * A p ----------------
  const float gs = 1.0f + g[0];
  for (int st = 0; st < NST; ++st) {
    load_stage(xp, stage, st, t);
    __syncthreads();
    const int i0 = wv * 32 + (db << 2);   // this lane's 4 i-values within tile
    float oa[8][4];
#pragma unroll
    for (int j = 0; j < 8; ++j)
#pragma unroll
      for (int v = 0; v < 4; ++v) oa[j][v] = 0.f;

#pragma unroll 4
    for (int d = 0; d < 64; ++d) {
      const float4 pv = *(const float4*)(&stage[d * SG + (i0 ^ ((d >> 3) << 2))]);
      const float4 aL = *(const float4*)(&AT[d * SA + cb * 8]);
      const float4 aH = *(const float4*)(&AT[d * SA + cb * 8 + 4]);
      const float as[8] = {aL.x, aL.y, aL.z, aL.w, aH.x, aH.y, aH.z, aH.w};
#pragma unroll
      for (int j = 0; j < 8; ++j) {
        oa[j][0] = fmaf(as[j], pv.x, oa[j][0]);
        oa[j][1] = fmaf(as[j], pv.y, oa[j][1]);
        oa[j][2] = fmaf(as[j], pv.z, oa[j][2]);
        oa[j][3] = fmaf(as[j], pv.w, oa[j][3]);
      }
    }

    const int gi = st * TI + i0;        // global i within patch
    const int r  = gi >> 6, cc = gi & 63;
#pragma unroll
    for (int j = 0; j < 8; ++j) {
      const int c = cb * 8 + j;
      const float4 o = make_float4(oa[j][0] * gs, oa[j][1] * gs, oa[j][2] * gs, oa[j][3] * gs);
      *(float4*)(op + (size_t)c * HWs + (size_t)r * NW + cc) = o;
    }
    __syncthreads();
  }
}

extern "C" void kernel_launch(void* const* d_in, const int* in_sizes, int n_in,
                              void* d_out, int out_size, void* d_ws, size_t ws_size,
                              hipStream_t stream) {
  const float* x = (const float*)d_in[0];
  const float* g = (const float*)d_in[1];
  float* o = (float*)d_out;
  spectralAgg_kernel<<<dim3(512), dim3(256), 0, stream>>>(x, g, o);
}

// Round 2
// 439.360 us; speedup vs baseline: 1.2396x; 1.2396x over previous
//
#include <hip/hip_runtime.h>

// spectralAgg via MFMA: per-(batch,patch) channel attention on 8x8 grid of 64x64
// patches of (8,64,512,512) fp32.
// E = p p^T (split-bf16: hi*hi^T + S + S^T, S = hi*lo^T), A = softmax(-E) rows,
// out = (1+gamma) * A p  (gamma folded into A, PV in bf16-hi via MFMA).

#define NC  64
#define NW  512
#define HWs 262144
#define NST 32

typedef __attribute__((ext_vector_type(8)))  __bf16 bf8;
typedef __attribute__((ext_vector_type(16))) float  f32x16;

__device__ __forceinline__ unsigned short bf16rne(float f) {
  unsigned int u = __float_as_uint(f);
  u += 0x7fffu + ((u >> 16) & 1u);
  return (unsigned short)(u >> 16);
}
__device__ __forceinline__ float fromb(unsigned short h) {
  return __uint_as_float(((unsigned int)h) << 16);
}

extern "C" __global__ __launch_bounds__(256, 4)
void spectralAgg_kernel(const float* __restrict__ x, const float* __restrict__ g,
                        float* __restrict__ out) {
  // 40KB LDS -> 4 WG/CU
  __shared__ char lds[40960];
  char* sH = lds;          // 16KB: hi stage, rows c: 256B (128 bf16). later E_lds f32[64][64], later stageT
  char* sL = lds + 16384;  // 16KB: lo stage. later S_lds f32[64][64]
  char* sA = lds + 32768;  // 8KB: AT bf16 [64 rows x 128B], swizzled

  const int t   = threadIdx.x;
  const int wv  = t >> 6;
  const int l   = t & 63;
  const int l31 = l & 31;
  const int hh  = l >> 5;

  const int wg = blockIdx.x;            // 512 = 8 batches * 64 patches
  const int b  = wg >> 6;
  const int pp = wg & 63;
  const int pr = pp >> 3, pc = pp & 7;
  const size_t pbase = (size_t)b * NC * HWs + (size_t)(pr * 64) * NW + (size_t)(pc * 64);
  const float* xp = x + pbase;
  float* op = out + pbase;

  // ================= Phase 1: Gram via split-bf16 MFMA =================
  const int ct = wv >> 1, dt = wv & 1;   // wave's E tile (32x32)
  f32x16 accG, accS;
#pragma unroll
  for (int r = 0; r < 16; ++r) { accG[r] = 0.f; accS[r] = 0.f; }

  const char* pA  = sH + (ct * 32 + l31) * 256;
  const char* pBh = sH + (dt * 32 + l31) * 256;
  const char* pBl = sL + (dt * 32 + l31) * 256;
  const int swzH = (l & 15) << 4;        // (row&15)<<4, same for pA/pBh/pBl rows

  for (int st = 0; st < NST; ++st) {
    // stage 64c x 128i fp32 -> hi/lo bf16 (swizzled)
#pragma unroll 4
    for (int k = 0; k < 8; ++k) {
      const int L = t + (k << 8);
      const int c = L >> 5, q = L & 31;
      const int rl = q >> 4, col = (q & 15) << 2;
      const float4 v = *(const float4*)(xp + (size_t)c * HWs + (size_t)(st * 2 + rl) * NW + col);
      const int i0  = rl * 64 + col;
      const int off = (c << 8) + (((i0 << 1)) ^ ((c & 15) << 4));
      const unsigned short h0 = bf16rne(v.x), h1 = bf16rne(v.y),
                           h2 = bf16rne(v.z), h3 = bf16rne(v.w);
      ushort4 hv; hv.x = h0; hv.y = h1; hv.z = h2; hv.w = h3;
      *(ushort4*)(sH + off) = hv;
      ushort4 lv;
      lv.x = bf16rne(v.x - fromb(h0));
      lv.y = bf16rne(v.y - fromb(h1));
      lv.z = bf16rne(v.z - fromb(h2));
      lv.w = bf16rne(v.w - fromb(h3));
      *(ushort4*)(sL + off) = lv;
    }
    __syncthreads();
#pragma unroll
    for (int k0 = 0; k0 < 8; ++k0) {
      const int off = ((k0 << 5) + (hh << 4)) ^ swzH;
      const bf8 a  = *(const bf8*)(pA  + off);
      const bf8 bh = *(const bf8*)(pBh + off);
      const bf8 bl = *(const bf8*)(pBl + off);
      accG = __builtin_amdgcn_mfma_f32_32x32x16_bf16(a, bh, accG, 0, 0, 0);
      accS = __builtin_amdgcn_mfma_f32_32x32x16_bf16(a, bl, accS, 0, 0, 0);
    }
    __syncthreads();
  }

  // ---- E = G + S + S^T (S to LDS, overlay sL; E to LDS, overlay sH) ----
  float* S_lds = (float*)sL;
  float* E_lds = (float*)sH;
#pragma unroll
  for (int r = 0; r < 16; ++r) {
    const int cr = ct * 32 + (r & 3) + ((r >> 2) << 3) + (hh << 2);
    S_lds[cr * 64 + dt * 32 + l31] = accS[r];
  }
  __syncthreads();
#pragma unroll
  for (int r = 0; r < 16; ++r) {
    const int cr = ct * 32 + (r & 3) + ((r >> 2) << 3) + (hh << 2);
    const int d  = dt * 32 + l31;
    E_lds[cr * 64 + d] = accG[r] + accS[r] + S_lds[d * 64 + cr];
  }
  __syncthreads();

  // ================= Phase 2: softmax(-E) rows -> AT (gamma folded) =====
  const float gs = 1.0f + g[0];
#pragma unroll 1
  for (int rr = 0; rr < 16; ++rr) {
    const int c = wv * 16 + rr;
    const float e = E_lds[c * 64 + l];
    float mn = e;
#pragma unroll
    for (int o = 32; o; o >>= 1) mn = fminf(mn, __shfl_xor(mn, o));
    const float w = __expf(mn - e);
    float s = w;
#pragma unroll
    for (int o = 32; o; o >>= 1) s += __shfl_xor(s, o);
    const float a = gs * w / s;
    *(unsigned short*)(sA + c * 128 + (((l << 1)) ^ ((c & 7) << 4))) = bf16rne(a);
  }
  __syncthreads();

  // ================= Phase 3: O^T[i][c] = sum_d p[d][i] A[c][d] =========
  char* sT = sH;                                   // transposed stage [128 i rows x 128B]
  const int irow = wv * 32 + l31;                  // lane's i row within stage
  const char* pP  = sT + irow * 128;
  const int swzT  = (((irow & 7) ^ ((irow >> 3) & 3)) << 4);
  const char* pA0 = sA + l31 * 128;                // c = l31
  const char* pA1 = sA + (32 + l31) * 128;         // c = 32 + l31
  const int swzA  = (l31 & 7) << 4;

  for (int st = 0; st < NST; ++st) {
    // stage transposed: thread does two 4x4 transposes (4 channels x 4 i)
#pragma unroll 2
    for (int k = 0; k < 2; ++k) {
      const int L = t + (k << 8);
      const int cg = L >> 5, q = L & 31;
      const int c0 = cg << 2;
      const int rl = q >> 4, col = (q & 15) << 2;
      const int i0 = rl * 64 + col;
      const float* gp = xp + (size_t)c0 * HWs + (size_t)(st * 2 + rl) * NW + col;
      const float4 v0 = *(const float4*)(gp);
      const float4 v1 = *(const float4*)(gp + HWs);
      const float4 v2 = *(const float4*)(gp + 2 * (size_t)HWs);
      const float4 v3 = *(const float4*)(gp + 3 * (size_t)HWs);
      float vv[4][4];
      vv[0][0] = v0.x; vv[0][1] = v0.y; vv[0][2] = v0.z; vv[0][3] = v0.w;
      vv[1][0] = v1.x; vv[1][1] = v1.y; vv[1][2] = v1.z; vv[1][3] = v1.w;
      vv[2][0] = v2.x; vv[2][1] = v2.y; vv[2][2] = v2.z; vv[2][3] = v2.w;
      vv[3][0] = v3.x; vv[3][1] = v3.y; vv[3][2] = v3.z; vv[3][3] = v3.w;
#pragma unroll
      for (int ii = 0; ii < 4; ++ii) {
        const int ir = i0 + ii;
        ushort4 wq;
        wq.x = bf16rne(vv[0][ii]); wq.y = bf16rne(vv[1][ii]);
        wq.z = bf16rne(vv[2][ii]); wq.w = bf16rne(vv[3][ii]);
        *(ushort4*)(sT + ir * 128 + (((c0 << 1)) ^ ((((ir & 7) ^ ((ir >> 3) & 3))) << 4))) = wq;
      }
    }
    __syncthreads();

    f32x16 o0, o1;
#pragma unroll
    for (int r = 0; r < 16; ++r) { o0[r] = 0.f; o1[r] = 0.f; }
#pragma unroll
    for (int k0 = 0; k0 < 4; ++k0) {
      const int km = (k0 << 5) + (hh << 4);
      const bf8 pa = *(const bf8*)(pP  + (km ^ swzT));
      const bf8 a0 = *(const bf8*)(pA0 + (km ^ swzA));
      const bf8 a1 = *(const bf8*)(pA1 + (km ^ swzA));
      o0 = __builtin_amdgcn_mfma_f32_32x32x16_bf16(pa, a0, o0, 0, 0, 0);
      o1 = __builtin_amdgcn_mfma_f32_32x32x16_bf16(pa, a1, o1, 0, 0, 0);
    }

    // store: lane's c = {l31, 32+l31}; i = wv*32 + 8*rq + 4*hh + (0..3)
#pragma unroll
    for (int rq = 0; rq < 4; ++rq) {
      const int iloc = wv * 32 + (rq << 3) + (hh << 2);
      const int grow = st * 2 + (iloc >> 6), gcol = iloc & 63;
      float* oprow = op + (size_t)grow * NW + gcol;
      float4 q0; q0.x = o0[rq * 4 + 0]; q0.y = o0[rq * 4 + 1];
                 q0.z = o0[rq * 4 + 2]; q0.w = o0[rq * 4 + 3];
      *(float4*)(oprow + (size_t)l31 * HWs) = q0;
      float4 q1; q1.x = o1[rq * 4 + 0]; q1.y = o1[rq * 4 + 1];
                 q1.z = o1[rq * 4 + 2]; q1.w = o1[rq * 4 + 3];
      *(float4*)(oprow + (size_t)(32 + l31) * HWs) = q1;
    }
    __syncthreads();
  }
}

extern "C" void kernel_launch(void* const* d_in, const int* in_sizes, int n_in,
                              void* d_out, int out_size, void* d_ws, size_t ws_size,
                              hipStream_t stream) {
  const float* x = (const float*)d_in[0];
  const float* g = (const float*)d_in[1];
  float* o = (float*)d_out;
  spectralAgg_kernel<<<dim3(512), dim3(256), 0, stream>>>(x, g, o);
}

// Round 3
// 388.078 us; speedup vs baseline: 1.4034x; 1.1321x over previous
//
#include <hip/hip_runtime.h>

// spectralAgg: per-(batch,patch) channel attention (DANet CAM), 8x8 grid of 64x64
// patches of (8,64,512,512) fp32.
// E = p p^T (split-bf16: G + S + S^T, S = hi*lo^T), A = softmax(-E) rows (gamma
// folded), out = A p via bf16 MFMA. Register double-buffered staging pipeline.

#define NW  512
#define HWs 262144
#define NS1 16          // phase-1 stages (64c x 256i each)
#define NS3 16          // phase-3 stages (256i x 64c each)

typedef __attribute__((ext_vector_type(8)))  __bf16 bf8;
typedef __attribute__((ext_vector_type(4)))  __bf16 bf4;
typedef __attribute__((ext_vector_type(16))) float  f32x16;

#define F4C(v, k) ((k) == 0 ? (v).x : (k) == 1 ? (v).y : (k) == 2 ? (v).z : (v).w)

__device__ __forceinline__ void load1(const float* g1, int st, float4 (&R)[16]) {
  const float* gp = g1 + (size_t)st * 4 * NW;
#pragma unroll
  for (int rl = 0; rl < 4; ++rl)
#pragma unroll
    for (int j = 0; j < 4; ++j)
      R[rl * 4 + j] = *(const float4*)(gp + (size_t)rl * NW + j * 4);
}

__device__ __forceinline__ void cvtw1(char* wH, char* wL, int q_ld, int swzw,
                                      const float4 (&R)[16]) {
#pragma unroll
  for (int rl = 0; rl < 4; ++rl)
#pragma unroll
    for (int s = 0; s < 2; ++s) {
      const float4 va = R[rl * 4 + s * 2], vb = R[rl * 4 + s * 2 + 1];
      const float f[8] = {va.x, va.y, va.z, va.w, vb.x, vb.y, vb.z, vb.w};
      bf8 h, lo;
#pragma unroll
      for (int e = 0; e < 8; ++e) {
        h[e]  = (__bf16)f[e];
        lo[e] = (__bf16)(f[e] - (float)h[e]);
      }
      const int boff = (rl * 128 + q_ld * 32 + s * 16) ^ swzw;
      *(bf8*)(wH + boff) = h;
      *(bf8*)(wL + boff) = lo;
    }
}

__device__ __forceinline__ void load3(const float* g3, int st, float4 (&R)[16]) {
  const float* gp = g3 + (size_t)st * 4 * NW;
#pragma unroll
  for (int cc = 0; cc < 4; ++cc)
#pragma unroll
    for (int j = 0; j < 4; ++j)
      R[cc * 4 + j] = *(const float4*)(gp + (size_t)cc * HWs + j * 4);
}

__device__ __forceinline__ void cvtw3(char* sT, int cg, int iq, const float4 (&R)[16]) {
#pragma unroll
  for (int w = 0; w < 16; ++w) {
    bf4 q;
#pragma unroll
    for (int cc = 0; cc < 4; ++cc)
      q[cc] = (__bf16)F4C(R[cc * 4 + (w >> 2)], w & 3);
    const int iloc = iq * 16 + w;
    const int boff = (iloc & 127) * 256 + (((((iloc >> 7) << 7)) + cg * 8) ^ (w << 4));
    *(bf4*)(sT + boff) = q;
  }
}

extern "C" __global__ __launch_bounds__(256, 2)
void spectralAgg_kernel(const float* __restrict__ x, const float* __restrict__ g,
                        float* __restrict__ out) {
  __shared__ char lds[73728];      // 72KB -> 2 WG/CU
  char* sH = lds;                  // 32KB hi stage / E_lds / sT overlay
  char* sL = lds + 32768;          // 32KB lo stage / S_lds overlay
  char* sA = lds + 65536;          // 8KB attention bf16 [64 c rows x 128B], swizzled

  const int t   = threadIdx.x;
  const int wv  = t >> 6;
  const int l   = t & 63;
  const int l31 = l & 31;
  const int hh  = l >> 5;

  const int wg = blockIdx.x;       // 512 = 8 batches * 64 patches
  const int b  = wg >> 6;
  const int pp = wg & 63;
  const int pr = pp >> 3, pc = pp & 7;
  const size_t pbase = (size_t)b * 64 * HWs + (size_t)(pr * 64) * NW + (size_t)(pc * 64);
  const float* xp = x + pbase;
  float* op = out + pbase;

  // ================= Phase 1: Gram via split-bf16 MFMA =================
  const int c_ld = t >> 2, q_ld = t & 3;
  const float* g1 = xp + (size_t)c_ld * HWs + q_ld * 16;
  char* wH = sH + c_ld * 512;
  char* wL = sL + c_ld * 512;
  const int swzw = (c_ld & 31) << 4;

  const int ct = wv >> 1, dt = wv & 1;     // wave's 32x32 E tile
  const char* pA  = sH + (size_t)(ct * 32 + l31) * 512;
  const char* pBh = sH + (size_t)(dt * 32 + l31) * 512;
  const char* pBl = sL + (size_t)(dt * 32 + l31) * 512;
  const int swzr = l31 << 4;               // (row&31)<<4 for all three

  f32x16 accG, accS;
#pragma unroll
  for (int r = 0; r < 16; ++r) { accG[r] = 0.f; accS[r] = 0.f; }

  float4 ra[16], rb[16];
  load1(g1, 0, ra);

  for (int st = 0; st < NS1; ++st) {
    load1(g1, (st + 1 < NS1) ? st + 1 : st, rb);   // prefetch next tile
    cvtw1(wH, wL, q_ld, swzw, ra);
    __syncthreads();
#pragma unroll
    for (int k0 = 0; k0 < 16; ++k0) {
      const int off = (k0 * 32 + hh * 16) ^ swzr;
      const bf8 a  = *(const bf8*)(pA  + off);
      const bf8 bh = *(const bf8*)(pBh + off);
      const bf8 bl = *(const bf8*)(pBl + off);
      accG = __builtin_amdgcn_mfma_f32_32x32x16_bf16(a, bh, accG, 0, 0, 0);
      accS = __builtin_amdgcn_mfma_f32_32x32x16_bf16(a, bl, accS, 0, 0, 0);
    }
    __syncthreads();
#pragma unroll
    for (int e = 0; e < 16; ++e) ra[e] = rb[e];
  }

  // ---- E = G + S + S^T (overlay staging buffers) ----
  float* S_lds = (float*)sL;
  float* E_lds = (float*)sH;
#pragma unroll
  for (int r = 0; r < 16; ++r) {
    const int cr = ct * 32 + (r & 3) + ((r >> 2) << 3) + (hh << 2);
    S_lds[cr * 64 + dt * 32 + l31] = accS[r];
  }
  __syncthreads();
#pragma unroll
  for (int r = 0; r < 16; ++r) {
    const int cr = ct * 32 + (r & 3) + ((r >> 2) << 3) + (hh << 2);
    const int d  = dt * 32 + l31;
    E_lds[cr * 64 + d] = accG[r] + accS[r] + S_lds[d * 64 + cr];
  }
  __syncthreads();

  // ============ Phase 2: softmax(-E) -> sA (phase-3 loads prefetched) ===
  const int cg = t >> 4, iq = t & 15;
  const float* g3 = xp + (size_t)(cg * 4) * HWs + (size_t)(iq >> 2) * NW + (iq & 3) * 16;
  load3(g3, 0, ra);                 // hide stage-0 latency under softmax

  const float gs = 1.0f + g[0];
#pragma unroll 1
  for (int rr = 0; rr < 16; ++rr) {
    const int c = wv * 16 + rr;
    const float e = E_lds[c * 64 + l];
    float mn = e;
#pragma unroll
    for (int o = 32; o; o >>= 1) mn = fminf(mn, __shfl_xor(mn, o));
    const float w = __expf(mn - e);
    float s = w;
#pragma unroll
    for (int o = 32; o; o >>= 1) s += __shfl_xor(s, o);
    const float a = gs * w / s;
    *(__bf16*)(sA + c * 128 + ((l * 2) ^ ((c & 7) << 4))) = (__bf16)a;
  }
  __syncthreads();

  // ================= Phase 3: O^T[i][c] = sum_d p[d][i] A[c][d] =========
  // B-fragments (A matrix) are stage-invariant: hoist into registers.
  bf8 bfr[2][4];
#pragma unroll
  for (int c2 = 0; c2 < 2; ++c2)
#pragma unroll
    for (int k0 = 0; k0 < 4; ++k0)
      bfr[c2][k0] = *(const bf8*)(sA + (size_t)(c2 * 32 + l31) * 128 +
                                  ((k0 * 32 + hh * 16) ^ ((l31 & 7) << 4)));

  for (int st = 0; st < NS3; ++st) {
    load3(g3, (st + 1 < NS3) ? st + 1 : st, rb);   // prefetch next tile
    cvtw3(sH, cg, iq, ra);
    __syncthreads();

    f32x16 oo[2][2];
#pragma unroll
    for (int it = 0; it < 2; ++it)
#pragma unroll
      for (int c2 = 0; c2 < 2; ++c2)
#pragma unroll
        for (int r = 0; r < 16; ++r) oo[it][c2][r] = 0.f;

#pragma unroll
    for (int it = 0; it < 2; ++it) {
      const int i = wv * 64 + it * 32 + l31;
      const char* base = sH + (size_t)(i & 127) * 256;
      const int hb = (i >> 7) * 128;
      const int sw = (i & 15) << 4;
#pragma unroll
      for (int k0 = 0; k0 < 4; ++k0) {
        const bf8 pa = *(const bf8*)(base + ((hb + k0 * 32 + hh * 16) ^ sw));
        oo[it][0] = __builtin_amdgcn_mfma_f32_32x32x16_bf16(pa, bfr[0][k0], oo[it][0], 0, 0, 0);
        oo[it][1] = __builtin_amdgcn_mfma_f32_32x32x16_bf16(pa, bfr[1][k0], oo[it][1], 0, 0, 0);
      }
    }

#pragma unroll
    for (int it = 0; it < 2; ++it)
#pragma unroll
      for (int c2 = 0; c2 < 2; ++c2) {
        const size_t cof = (size_t)(c2 * 32 + l31) * HWs;
#pragma unroll
        for (int rq = 0; rq < 4; ++rq) {
          const int iloc = wv * 64 + it * 32 + rq * 8 + hh * 4;
          const int grow = st * 4 + (iloc >> 6), gcol = iloc & 63;
          float4 q;
          q.x = oo[it][c2][rq * 4 + 0];
          q.y = oo[it][c2][rq * 4 + 1];
          q.z = oo[it][c2][rq * 4 + 2];
          q.w = oo[it][c2][rq * 4 + 3];
          *(float4*)(op + cof + (size_t)grow * NW + gcol) = q;
        }
      }
    __syncthreads();
#pragma unroll
    for (int e = 0; e < 16; ++e) ra[e] = rb[e];
  }
}

extern "C" void kernel_launch(void* const* d_in, const int* in_sizes, int n_in,
                              void* d_out, int out_size, void* d_ws, size_t ws_size,
                              hipStream_t stream) {
  const float* x = (const float*)d_in[0];
  const float* g = (const float*)d_in[1];
  float* o = (float*)d_out;
  spectralAgg_kernel<<<dim3(512), dim3(256), 0, stream>>>(x, g, o);
}

// Round 4
// 377.984 us; speedup vs baseline: 1.4408x; 1.0267x over previous
//
#include <hip/hip_runtime.h>

// spectralAgg: per-(batch,patch) channel attention (DANet CAM), 8x8 grid of 64x64
// patches of (8,64,512,512) fp32.
// E = p p^T (split-bf16: G + S + S^T, S = hi*lo^T), A = softmax(-E) rows (gamma
// folded), out = A p via bf16 MFMA.
// R4: raw s_barrier + lgkmcnt(0) only (no vmcnt drain -> global prefetch lives
// across barriers, T3/T4 principle); phase-3 LDS swizzle includes (i>>4) so
// staging writes are bank-minimal.

#define NW  512
#define HWs 262144
#define NS1 16          // phase-1 stages (64c x 256i each)
#define NS3 16          // phase-3 stages (256i x 64c each)

typedef __attribute__((ext_vector_type(8)))  __bf16 bf8;
typedef __attribute__((ext_vector_type(4)))  __bf16 bf4;
typedef __attribute__((ext_vector_type(16))) float  f32x16;

#define F4C(v, k) ((k) == 0 ? (v).x : (k) == 1 ? (v).y : (k) == 2 ? (v).z : (v).w)

// barrier that waits only LDS ops: global loads stay in flight (prefetch pipeline)
__device__ __forceinline__ void bar_lgkm() {
  asm volatile("s_waitcnt lgkmcnt(0)" ::: "memory");
  __builtin_amdgcn_s_barrier();
}

__device__ __forceinline__ void load1(const float* g1, int st, float4 (&R)[16]) {
  const float* gp = g1 + (size_t)st * 4 * NW;
#pragma unroll
  for (int rl = 0; rl < 4; ++rl)
#pragma unroll
    for (int j = 0; j < 4; ++j)
      R[rl * 4 + j] = *(const float4*)(gp + (size_t)rl * NW + j * 4);
}

__device__ __forceinline__ void cvtw1(char* wH, char* wL, int q_ld, int swzw,
                                      const float4 (&R)[16]) {
#pragma unroll
  for (int rl = 0; rl < 4; ++rl)
#pragma unroll
    for (int s = 0; s < 2; ++s) {
      const float4 va = R[rl * 4 + s * 2], vb = R[rl * 4 + s * 2 + 1];
      const float f[8] = {va.x, va.y, va.z, va.w, vb.x, vb.y, vb.z, vb.w};
      bf8 h, lo;
#pragma unroll
      for (int e = 0; e < 8; ++e) {
        h[e]  = (__bf16)f[e];
        lo[e] = (__bf16)(f[e] - (float)h[e]);
      }
      const int boff = (rl * 128 + q_ld * 32 + s * 16) ^ swzw;
      *(bf8*)(wH + boff) = h;
      *(bf8*)(wL + boff) = lo;
    }
}

__device__ __forceinline__ void load3(const float* g3, int st, float4 (&R)[16]) {
  const float* gp = g3 + (size_t)st * 4 * NW;
#pragma unroll
  for (int cc = 0; cc < 4; ++cc)
#pragma unroll
    for (int j = 0; j < 4; ++j)
      R[cc * 4 + j] = *(const float4*)(gp + (size_t)cc * HWs + j * 4);
}

__device__ __forceinline__ void cvtw3(char* sT, int cg, int iq, const float4 (&R)[16]) {
#pragma unroll
  for (int w = 0; w < 16; ++w) {
    bf4 q;
#pragma unroll
    for (int cc = 0; cc < 4; ++cc)
      q[cc] = (__bf16)F4C(R[cc * 4 + (w >> 2)], w & 3);
    const int iloc = iq * 16 + w;
    const int sw   = ((iloc & 15) ^ ((iloc >> 4) & 7)) << 4;   // iq-dependent: kills 4x write conflict
    const int boff = (iloc & 127) * 256 + ((((iloc >> 7) << 7) + cg * 8) ^ sw);
    *(bf4*)(sT + boff) = q;
  }
}

extern "C" __global__ __launch_bounds__(256, 2)
void spectralAgg_kernel(const float* __restrict__ x, const float* __restrict__ g,
                        float* __restrict__ out) {
  __shared__ char lds[73728];      // 72KB -> 2 WG/CU
  char* sH = lds;                  // 32KB hi stage / E_lds / sT overlay
  char* sL = lds + 32768;          // 32KB lo stage / S_lds overlay
  char* sA = lds + 65536;          // 8KB attention bf16 [64 c rows x 128B], swizzled

  const int t   = threadIdx.x;
  const int wv  = t >> 6;
  const int l   = t & 63;
  const int l31 = l & 31;
  const int hh  = l >> 5;

  const int wg = blockIdx.x;       // 512 = 8 batches * 64 patches
  const int b  = wg >> 6;
  const int pp = wg & 63;
  const int pr = pp >> 3, pc = pp & 7;
  const size_t pbase = (size_t)b * 64 * HWs + (size_t)(pr * 64) * NW + (size_t)(pc * 64);
  const float* xp = x + pbase;
  float* op = out + pbase;

  // ================= Phase 1: Gram via split-bf16 MFMA =================
  const int c_ld = t >> 2, q_ld = t & 3;
  const float* g1 = xp + (size_t)c_ld * HWs + q_ld * 16;
  char* wH = sH + c_ld * 512;
  char* wL = sL + c_ld * 512;
  const int swzw = (c_ld & 31) << 4;

  const int ct = wv >> 1, dt = wv & 1;     // wave's 32x32 E tile
  const char* pA  = sH + (size_t)(ct * 32 + l31) * 512;
  const char* pBh = sH + (size_t)(dt * 32 + l31) * 512;
  const char* pBl = sL + (size_t)(dt * 32 + l31) * 512;
  const int swzr = l31 << 4;               // (row&31)<<4 for all three

  f32x16 accG, accS;
#pragma unroll
  for (int r = 0; r < 16; ++r) { accG[r] = 0.f; accS[r] = 0.f; }

  float4 ra[16], rb[16];
  load1(g1, 0, ra);

  for (int st = 0; st < NS1; ++st) {
    load1(g1, (st + 1 < NS1) ? st + 1 : st, rb);   // prefetch: stays in flight across barriers
    cvtw1(wH, wL, q_ld, swzw, ra);
    bar_lgkm();
#pragma unroll
    for (int k0 = 0; k0 < 16; ++k0) {
      const int off = (k0 * 32 + hh * 16) ^ swzr;
      const bf8 a  = *(const bf8*)(pA  + off);
      const bf8 bh = *(const bf8*)(pBh + off);
      const bf8 bl = *(const bf8*)(pBl + off);
      accG = __builtin_amdgcn_mfma_f32_32x32x16_bf16(a, bh, accG, 0, 0, 0);
      accS = __builtin_amdgcn_mfma_f32_32x32x16_bf16(a, bl, accS, 0, 0, 0);
    }
    bar_lgkm();
#pragma unroll
    for (int e = 0; e < 16; ++e) ra[e] = rb[e];
  }

  // ---- E = G + S + S^T (overlay staging buffers) ----
  float* S_lds = (float*)sL;
  float* E_lds = (float*)sH;
#pragma unroll
  for (int r = 0; r < 16; ++r) {
    const int cr = ct * 32 + (r & 3) + ((r >> 2) << 3) + (hh << 2);
    S_lds[cr * 64 + dt * 32 + l31] = accS[r];
  }
  bar_lgkm();
#pragma unroll
  for (int r = 0; r < 16; ++r) {
    const int cr = ct * 32 + (r & 3) + ((r >> 2) << 3) + (hh << 2);
    const int d  = dt * 32 + l31;
    E_lds[cr * 64 + d] = accG[r] + accS[r] + S_lds[d * 64 + cr];
  }
  bar_lgkm();

  // ============ Phase 2: softmax(-E) -> sA (phase-3 loads prefetched) ===
  const int cg = t >> 4, iq = t & 15;
  const float* g3 = xp + (size_t)(cg * 4) * HWs + (size_t)(iq >> 2) * NW + (iq & 3) * 16;
  load3(g3, 0, ra);                 // hide stage-0 latency under softmax

  const float gs = 1.0f + g[0];
#pragma unroll 1
  for (int rr = 0; rr < 16; ++rr) {
    const int c = wv * 16 + rr;
    const float e = E_lds[c * 64 + l];
    float mn = e;
#pragma unroll
    for (int o = 32; o; o >>= 1) mn = fminf(mn, __shfl_xor(mn, o));
    const float w = __expf(mn - e);
    float s = w;
#pragma unroll
    for (int o = 32; o; o >>= 1) s += __shfl_xor(s, o);
    const float a = gs * w / s;
    *(__bf16*)(sA + c * 128 + ((l * 2) ^ ((c & 7) << 4))) = (__bf16)a;
  }
  bar_lgkm();

  // ================= Phase 3: O^T[i][c] = sum_d p[d][i] A[c][d] =========
  // B-fragments (A matrix) are stage-invariant: hoist into registers.
  bf8 bfr[2][4];
#pragma unroll
  for (int c2 = 0; c2 < 2; ++c2)
#pragma unroll
    for (int k0 = 0; k0 < 4; ++k0)
      bfr[c2][k0] = *(const bf8*)(sA + (size_t)(c2 * 32 + l31) * 128 +
                                  ((k0 * 32 + hh * 16) ^ ((l31 & 7) << 4)));

  for (int st = 0; st < NS3; ++st) {
    load3(g3, (st + 1 < NS3) ? st + 1 : st, rb);   // prefetch next tile
    cvtw3(sH, cg, iq, ra);
    bar_lgkm();

    f32x16 oo[2][2];
#pragma unroll
    for (int it = 0; it < 2; ++it)
#pragma unroll
      for (int c2 = 0; c2 < 2; ++c2)
#pragma unroll
        for (int r = 0; r < 16; ++r) oo[it][c2][r] = 0.f;

#pragma unroll
    for (int it = 0; it < 2; ++it) {
      const int i = wv * 64 + it * 32 + l31;
      const char* base = sH + (size_t)(i & 127) * 256;
      const int hb = (i >> 7) * 128;
      const int sw = ((i & 15) ^ ((i >> 4) & 7)) << 4;    // must match cvtw3
#pragma unroll
      for (int k0 = 0; k0 < 4; ++k0) {
        const bf8 pa = *(const bf8*)(base + ((hb + k0 * 32 + hh * 16) ^ sw));
        oo[it][0] = __builtin_amdgcn_mfma_f32_32x32x16_bf16(pa, bfr[0][k0], oo[it][0], 0, 0, 0);
        oo[it][1] = __builtin_amdgcn_mfma_f32_32x32x16_bf16(pa, bfr[1][k0], oo[it][1], 0, 0, 0);
      }
    }

#pragma unroll
    for (int it = 0; it < 2; ++it)
#pragma unroll
      for (int c2 = 0; c2 < 2; ++c2) {
        const size_t cof = (size_t)(c2 * 32 + l31) * HWs;
#pragma unroll
        for (int rq = 0; rq < 4; ++rq) {
          const int iloc = wv * 64 + it * 32 + rq * 8 + hh * 4;
          const int grow = st * 4 + (iloc >> 6), gcol = iloc & 63;
          float4 q;
          q.x = oo[it][c2][rq * 4 + 0];
          q.y = oo[it][c2][rq * 4 + 1];
          q.z = oo[it][c2][rq * 4 + 2];
          q.w = oo[it][c2][rq * 4 + 3];
          *(float4*)(op + cof + (size_t)grow * NW + gcol) = q;
        }
      }
    bar_lgkm();
#pragma unroll
    for (int e = 0; e < 16; ++e) ra[e] = rb[e];
  }
}

extern "C" void kernel_launch(void* const* d_in, const int* in_sizes, int n_in,
                              void* d_out, int out_size, void* d_ws, size_t ws_size,
                              hipStream_t stream) {
  const float* x = (const float*)d_in[0];
  const float* g = (const float*)d_in[1];
  float* o = (float*)d_out;
  spectralAgg_kernel<<<dim3(512), dim3(256), 0, stream>>>(x, g, o);
}